// Round 6
// baseline (185.243 us; speedup 1.0000x reference)
//
#include <hip/hip_runtime.h>

typedef __attribute__((ext_vector_type(8))) short bf16x8;
typedef __attribute__((ext_vector_type(4))) float f32x4;

// fp32 -> bf16 (round-to-nearest-even), finite inputs only
__device__ __forceinline__ unsigned short f2b(float f) {
  union { float f; unsigned u; } v; v.f = f;
  return (unsigned short)((v.u + 0x7FFFu + ((v.u >> 16) & 1u)) >> 16);
}
// cheap round-half-up (for P only; half-ULP bias cancels in softmax ratio)
__device__ __forceinline__ unsigned short f2b_fast(float f) {
  union { float f; unsigned u; } v; v.f = f;
  return (unsigned short)((v.u + 0x8000u) >> 16);
}

// Fused fp32->bf16 cast for x, W_attn, W_proj (one launch)
#define XN4   786432   // 4096*768/4
#define WAN4  442368   // 2304*768/4
#define WPN4  147456   // 768*768/4
__global__ void cvt_all(const float* __restrict__ x, const float* __restrict__ Wa,
                        const float* __restrict__ Wp,
                        unsigned short* __restrict__ xb, unsigned short* __restrict__ Wab,
                        unsigned short* __restrict__ Wpb) {
  int i = blockIdx.x * 256 + threadIdx.x;
  const float* src; unsigned short* dst; int off;
  if (i < XN4)            { src = x;  dst = xb;  off = i; }
  else if (i < XN4 + WAN4){ src = Wa; dst = Wab; off = i - XN4; }
  else                    { src = Wp; dst = Wpb; off = i - XN4 - WAN4; }
  float4 f = reinterpret_cast<const float4*>(src)[off];
  ushort4 o;
  o.x = f2b(f.x); o.y = f2b(f.y); o.z = f2b(f.z); o.w = f2b(f.w);
  reinterpret_cast<ushort4*>(dst)[off] = o;
}

// qkv = x @ W_attn^T (A:[4096][768], B:[2304][768], both bf16 row-major).
// 128x128x64 tiles, global_load_lds width-16, XOR-swizzled LDS chunks.
// Epilogue scatters to Qb(*scale2)/Kb [BH][T][64]; for V-blocks
// (blockIdx.y>=12) the MFMA operands are SWAPPED so D = [f][t] and the
// Vt [BH][64][T] store is contiguous in t (32B per quad vs 2B scatter).
#define BK 64

__global__ __launch_bounds__(256, 2)
void gemm_qkv(const unsigned short* __restrict__ A,
              const unsigned short* __restrict__ Bm,
              unsigned short* __restrict__ qb,
              unsigned short* __restrict__ kb_,
              unsigned short* __restrict__ vt) {
  __shared__ unsigned short As[128 * 64];  // 16 KB
  __shared__ unsigned short Bs[128 * 64];  // 16 KB
  const int K = 768;
  int tid = threadIdx.x;
  int wave = tid >> 6, lane = tid & 63;
  int quad = lane >> 4, l16 = lane & 15;
  int m0 = blockIdx.x * 128, n0 = blockIdx.y * 128;
  int wm = (wave & 1) * 64, wn = (wave >> 1) * 64;
  bool vswap = (n0 >= 1536);

  int srow = lane >> 3;                   // 0..7
  int scol = ((lane & 7) ^ srow) << 3;    // swizzled global chunk * 8 elems

  f32x4 acc[4][4] = {};

  for (int k0 = 0; k0 < K; k0 += BK) {
    __syncthreads();
#pragma unroll
    for (int i = 0; i < 4; ++i) {
      int r = wave * 32 + i * 8;
      __builtin_amdgcn_global_load_lds(
          (const __attribute__((address_space(1))) unsigned int*)(A + (size_t)(m0 + r + srow) * K + k0 + scol),
          (__attribute__((address_space(3))) unsigned int*)(As + r * 64), 16, 0, 0);
      __builtin_amdgcn_global_load_lds(
          (const __attribute__((address_space(1))) unsigned int*)(Bm + (size_t)(n0 + r + srow) * K + k0 + scol),
          (__attribute__((address_space(3))) unsigned int*)(Bs + r * 64), 16, 0, 0);
    }
    __syncthreads();
#pragma unroll
    for (int kb = 0; kb < 2; ++kb) {
      int ch = (((kb << 2) | quad) ^ (l16 & 7)) << 3;
      bf16x8 af[4], bf[4];
#pragma unroll
      for (int i = 0; i < 4; ++i)
        af[i] = *reinterpret_cast<const bf16x8*>(As + (wm + i * 16 + l16) * 64 + ch);
#pragma unroll
      for (int j = 0; j < 4; ++j)
        bf[j] = *reinterpret_cast<const bf16x8*>(Bs + (wn + j * 16 + l16) * 64 + ch);
      if (!vswap) {
#pragma unroll
        for (int i = 0; i < 4; ++i)
#pragma unroll
          for (int j = 0; j < 4; ++j)
            acc[i][j] = __builtin_amdgcn_mfma_f32_16x16x32_bf16(af[i], bf[j], acc[i][j], 0, 0, 0);
      } else {
#pragma unroll
        for (int i = 0; i < 4; ++i)
#pragma unroll
          for (int j = 0; j < 4; ++j)
            acc[i][j] = __builtin_amdgcn_mfma_f32_16x16x32_bf16(bf[j], af[i], acc[i][j], 0, 0, 0);
      }
    }
  }

  const float scale2 = 0.125f * 1.44269504089f;  // 1/sqrt(64) * log2(e), folded into Q
  if (!vswap) {
    // D rows = t-side, cols = f-side (Q/K only here since n0<1536)
#pragma unroll
    for (int i = 0; i < 4; ++i) {
      int mbase = m0 + wm + i * 16 + quad * 4;
#pragma unroll
      for (int j = 0; j < 4; ++j) {
        int f = n0 + wn + j * 16 + l16;
        int which = f / 768;
        int f2 = f - which * 768;
        int h = f2 >> 6, d = f2 & 63;
#pragma unroll
        for (int r = 0; r < 4; ++r) {
          int m = mbase + r;
          int b = m >> 11, t = m & 2047;
          int bh = b * 12 + h;
          if (which == 0) qb[((size_t)(bh * 2048 + t)) * 64 + d] = f2b(acc[i][j][r] * scale2);
          else            kb_[((size_t)(bh * 2048 + t)) * 64 + d] = f2b(acc[i][j][r]);
        }
      }
    }
  } else {
    // D rows = f-side, cols = t-side -> Vt store contiguous in t
#pragma unroll
    for (int j = 0; j < 4; ++j) {
      int fbase = n0 + wn + j * 16 + quad * 4 - 1536;
#pragma unroll
      for (int i = 0; i < 4; ++i) {
        int t_g = m0 + wm + i * 16 + l16;
        int b = t_g >> 11, t = t_g & 2047;
#pragma unroll
        for (int r = 0; r < 4; ++r) {
          int f2 = fbase + r;
          int h = f2 >> 6, d = f2 & 63;
          int bh = b * 12 + h;
          vt[((size_t)(bh * 64 + d)) * 2048 + t] = f2b(acc[i][j][r]);
        }
      }
    }
  }
}

// ---------------- Split-K flash attention, GEMM-shaped ----------------
// Block = 4 waves on one (bh, 128-row Q-block, 512-key chunk). K/V tiles
// staged via global_load_lds width-16. No-max softmax (m=0 fixed, Q
// pre-scaled); row-sum via ones-MFMA. Partials atomicAdd into fp32
// Oacc/Lacc (zeroed up front). LDS exactly 32 KB -> 5 blocks/CU.
#define CK 512

__global__ __launch_bounds__(256, 4)
void attn_part(const unsigned short* __restrict__ Qb,
               const unsigned short* __restrict__ Kb,
               const unsigned short* __restrict__ Vt,
               float* __restrict__ Oacc, float* __restrict__ Lacc) {
  __shared__ unsigned short Ks[64 * 64];   // 8 KB
  __shared__ unsigned short Vs[64 * 64];   // 8 KB
  __shared__ unsigned short P[4 * 32 * 64];// 16 KB, xor-swizzled chunks
  const int T = 2048, D = 64;
  int wave = threadIdx.x >> 6, lane = threadIdx.x & 63;
  int quad = lane >> 4, l16 = lane & 15;

  // decode block -> (bh, qblock b, chunk c): per bh, 40 (b,c) pairs
  int w = blockIdx.x;
  int bh = w / 40;
  int r = w - bh * 40;
  int b = 15;
#pragma unroll
  for (int i = 0; i < 16; ++i) {
    int nb = (i >> 2) + 1;
    if (r < nb) { b = i; break; }
    r -= nb;
  }
  int c = r;
  int q0 = b * 128;
  int qrow = q0 + wave * 32;
  int kbeg = c * CK;
  int kend = kbeg + CK; if (kend > q0 + 128) kend = q0 + 128;

  const unsigned short* Qp = Qb + (size_t)bh * T * D;
  const unsigned short* Kp = Kb + (size_t)bh * T * D;
  const unsigned short* Vp = Vt + (size_t)bh * D * T;
  unsigned short* Pw = P + wave * 32 * 64;

  int srow = lane >> 3;
  int scol = ((lane & 7) ^ srow) << 3;

  bf16x8 aq[2][2];
#pragma unroll
  for (int qi = 0; qi < 2; ++qi)
#pragma unroll
    for (int cc = 0; cc < 2; ++cc)
      aq[qi][cc] = *reinterpret_cast<const bf16x8*>(
          Qp + (qrow + qi * 16 + l16) * D + cc * 32 + quad * 8);

  bf16x8 ones;
#pragma unroll
  for (int e = 0; e < 8; ++e) ones[e] = (short)0x3F80;  // bf16 1.0

  f32x4 o[2][4] = {};
  f32x4 lacc[2] = {};
  int pswr = (l16 & 7) ^ (l16 >> 3);  // P-read row swizzle

  for (int k0 = kbeg; k0 < kend; k0 += 64) {
    __syncthreads();
#pragma unroll
    for (int i = 0; i < 2; ++i) {
      int rr = wave * 16 + i * 8;
      __builtin_amdgcn_global_load_lds(
          (const __attribute__((address_space(1))) unsigned int*)(Kp + (size_t)(k0 + rr + srow) * D + scol),
          (__attribute__((address_space(3))) unsigned int*)(Ks + rr * 64), 16, 0, 0);
      __builtin_amdgcn_global_load_lds(
          (const __attribute__((address_space(1))) unsigned int*)(Vp + (size_t)(rr + srow) * T + k0 + scol),
          (__attribute__((address_space(3))) unsigned int*)(Vs + rr * 64), 16, 0, 0);
    }
    __syncthreads();

    if (k0 > qrow + 31) continue;  // fully masked for this wave (barriers uniform)

    // ---- S = Q K^T ----
    f32x4 sacc[2][4] = {};
#pragma unroll
    for (int nt = 0; nt < 4; ++nt) {
      bf16x8 bk0 = *reinterpret_cast<const bf16x8*>(Ks + (nt * 16 + l16) * 64 + ((quad ^ (l16 & 7)) << 3));
      bf16x8 bk1 = *reinterpret_cast<const bf16x8*>(Ks + (nt * 16 + l16) * 64 + (((4 | quad) ^ (l16 & 7)) << 3));
#pragma unroll
      for (int qi = 0; qi < 2; ++qi) {
        sacc[qi][nt] = __builtin_amdgcn_mfma_f32_16x16x32_bf16(aq[qi][0], bk0, sacc[qi][nt], 0, 0, 0);
        sacc[qi][nt] = __builtin_amdgcn_mfma_f32_16x16x32_bf16(aq[qi][1], bk1, sacc[qi][nt], 0, 0, 0);
      }
    }

    // ---- p = 2^s ; mask only diagonal-straddling tiles ----
    if (k0 + 63 > qrow) {
#pragma unroll
      for (int qi = 0; qi < 2; ++qi)
#pragma unroll
        for (int nt = 0; nt < 4; ++nt) {
          int col = k0 + nt * 16 + l16;
#pragma unroll
          for (int rr = 0; rr < 4; ++rr) {
            int row = qrow + qi * 16 + quad * 4 + rr;
            sacc[qi][nt][rr] = (col <= row) ? sacc[qi][nt][rr] : -1e30f;
          }
        }
    }
#pragma unroll
    for (int qi = 0; qi < 2; ++qi)
#pragma unroll
      for (int nt = 0; nt < 4; ++nt)
#pragma unroll
        for (int rr = 0; rr < 4; ++rr)
          sacc[qi][nt][rr] = exp2f(sacc[qi][nt][rr]);

    // ---- P: C-layout -> wave-private LDS (swizzled) -> A-layout ----
#pragma unroll
    for (int qi = 0; qi < 2; ++qi)
#pragma unroll
      for (int rr = 0; rr < 4; ++rr) {
        int prow = qi * 16 + quad * 4 + rr;
        int psw = (prow & 7) ^ ((prow >> 3) & 1);
#pragma unroll
        for (int nt = 0; nt < 4; ++nt)
          Pw[prow * 64 + (((nt * 2 + (l16 >> 3)) ^ psw) << 3) + (l16 & 7)] = f2b_fast(sacc[qi][nt][rr]);
      }
    __asm__ volatile("s_waitcnt lgkmcnt(0)" ::: "memory");

    // ---- O += P V ; l += P * ones ----
    bf16x8 vf[4][2];
#pragma unroll
    for (int dt = 0; dt < 4; ++dt) {
      vf[dt][0] = *reinterpret_cast<const bf16x8*>(Vs + (dt * 16 + l16) * 64 + ((quad ^ (l16 & 7)) << 3));
      vf[dt][1] = *reinterpret_cast<const bf16x8*>(Vs + (dt * 16 + l16) * 64 + (((4 | quad) ^ (l16 & 7)) << 3));
    }
#pragma unroll
    for (int qi = 0; qi < 2; ++qi) {
      bf16x8 ap0 = *reinterpret_cast<const bf16x8*>(Pw + (qi * 16 + l16) * 64 + ((quad ^ pswr) << 3));
      bf16x8 ap1 = *reinterpret_cast<const bf16x8*>(Pw + (qi * 16 + l16) * 64 + (((4 | quad) ^ pswr) << 3));
#pragma unroll
      for (int dt = 0; dt < 4; ++dt) {
        o[qi][dt] = __builtin_amdgcn_mfma_f32_16x16x32_bf16(ap0, vf[dt][0], o[qi][dt], 0, 0, 0);
        o[qi][dt] = __builtin_amdgcn_mfma_f32_16x16x32_bf16(ap1, vf[dt][1], o[qi][dt], 0, 0, 0);
      }
      lacc[qi] = __builtin_amdgcn_mfma_f32_16x16x32_bf16(ap0, ones, lacc[qi], 0, 0, 0);
      lacc[qi] = __builtin_amdgcn_mfma_f32_16x16x32_bf16(ap1, ones, lacc[qi], 0, 0, 0);
    }
  }

  // accumulate partials: fp32 atomics (plain sums combine exactly, m fixed)
#pragma unroll
  for (int qi = 0; qi < 2; ++qi)
#pragma unroll
    for (int dt = 0; dt < 4; ++dt)
#pragma unroll
      for (int rr = 0; rr < 4; ++rr) {
        int row = qrow + qi * 16 + quad * 4 + rr;
        atomicAdd(&Oacc[((size_t)(bh * T + row)) * 64 + dt * 16 + l16], o[qi][dt][rr]);
      }
  if (l16 == 0) {
#pragma unroll
    for (int qi = 0; qi < 2; ++qi)
#pragma unroll
      for (int rr = 0; rr < 4; ++rr)
        atomicAdd(&Lacc[bh * T + qrow + qi * 16 + quad * 4 + rr], lacc[qi][rr]);
  }
}

// out = normalize(Oacc/Lacc) @ W_proj^T, fp32 out. 64x128x64 tiles, 384
// blocks. A-tile built in VGPRs (load Oacc fp32, *1/L, cvt bf16, ds_write);
// B-tile via global_load_lds. Fuses attn_norm.
__global__ __launch_bounds__(256, 2)
void gemm_proj(const float* __restrict__ Oacc, const float* __restrict__ Lacc,
               const unsigned short* __restrict__ Wpb, float* __restrict__ out) {
  __shared__ unsigned short As[64 * 64];   // 8 KB
  __shared__ unsigned short Bs[128 * 64];  // 16 KB
  int tid = threadIdx.x;
  int wave = tid >> 6, lane = tid & 63;
  int quad = lane >> 4, l16 = lane & 15;
  int m0 = blockIdx.x * 64, n0 = blockIdx.y * 128;
  int wm = (wave & 1) * 32, wn = (wave >> 1) * 64;

  int srow = lane >> 3;
  int scol = ((lane & 7) ^ srow) << 3;

  // A staging assignment: thread -> (row, 16-col group)
  int arow = tid >> 2;           // 0..63
  int acg = (tid & 3) * 2;       // logical chunk pair: cols acg*8 .. acg*8+15
  int t_g = m0 + arow;
  int bb = t_g >> 11, tt = t_g & 2047;
  int asw = arow & 7;

  f32x4 acc[2][4] = {};

  for (int k0 = 0; k0 < 768; k0 += BK) {
    int h = k0 >> 6;
    const float* arp = Oacc + ((size_t)((bb * 12 + h) * 2048 + tt)) * 64 + acg * 8;
    float rl = 1.0f / Lacc[(bb * 12 + h) * 2048 + tt];
    float4 a0 = reinterpret_cast<const float4*>(arp)[0];
    float4 a1 = reinterpret_cast<const float4*>(arp)[1];
    float4 a2 = reinterpret_cast<const float4*>(arp)[2];
    float4 a3 = reinterpret_cast<const float4*>(arp)[3];

    __syncthreads();
#pragma unroll
    for (int i = 0; i < 4; ++i) {
      int r = wave * 32 + i * 8;
      __builtin_amdgcn_global_load_lds(
          (const __attribute__((address_space(1))) unsigned int*)(Wpb + (size_t)(n0 + r + srow) * 768 + k0 + scol),
          (__attribute__((address_space(3))) unsigned int*)(Bs + r * 64), 16, 0, 0);
    }
    bf16x8 p0, p1;
    p0[0] = (short)f2b(a0.x * rl); p0[1] = (short)f2b(a0.y * rl);
    p0[2] = (short)f2b(a0.z * rl); p0[3] = (short)f2b(a0.w * rl);
    p0[4] = (short)f2b(a1.x * rl); p0[5] = (short)f2b(a1.y * rl);
    p0[6] = (short)f2b(a1.z * rl); p0[7] = (short)f2b(a1.w * rl);
    p1[0] = (short)f2b(a2.x * rl); p1[1] = (short)f2b(a2.y * rl);
    p1[2] = (short)f2b(a2.z * rl); p1[3] = (short)f2b(a2.w * rl);
    p1[4] = (short)f2b(a3.x * rl); p1[5] = (short)f2b(a3.y * rl);
    p1[6] = (short)f2b(a3.z * rl); p1[7] = (short)f2b(a3.w * rl);
    *reinterpret_cast<bf16x8*>(As + arow * 64 + ((acg ^ asw) << 3)) = p0;
    *reinterpret_cast<bf16x8*>(As + arow * 64 + (((acg + 1) ^ asw) << 3)) = p1;
    __syncthreads();

#pragma unroll
    for (int kb = 0; kb < 2; ++kb) {
      int ch = (((kb << 2) | quad) ^ (l16 & 7)) << 3;
      bf16x8 af[2], bf[4];
#pragma unroll
      for (int i = 0; i < 2; ++i)
        af[i] = *reinterpret_cast<const bf16x8*>(As + (wm + i * 16 + l16) * 64 + ch);
#pragma unroll
      for (int j = 0; j < 4; ++j)
        bf[j] = *reinterpret_cast<const bf16x8*>(Bs + (wn + j * 16 + l16) * 64 + ch);
#pragma unroll
      for (int i = 0; i < 2; ++i)
#pragma unroll
        for (int j = 0; j < 4; ++j)
          acc[i][j] = __builtin_amdgcn_mfma_f32_16x16x32_bf16(af[i], bf[j], acc[i][j], 0, 0, 0);
    }
  }

#pragma unroll
  for (int i = 0; i < 2; ++i) {
    int mbase = m0 + wm + i * 16 + quad * 4;
#pragma unroll
    for (int j = 0; j < 4; ++j) {
      int col = n0 + wn + j * 16 + l16;
#pragma unroll
      for (int r = 0; r < 4; ++r)
        out[(size_t)(mbase + r) * 768 + col] = acc[i][j][r];
    }
  }
}

extern "C" void kernel_launch(void* const* d_in, const int* in_sizes, int n_in,
                              void* d_out, int out_size, void* d_ws, size_t ws_size,
                              hipStream_t stream) {
  const float* x  = (const float*)d_in[0];   // [2,2048,768]
  const float* Wa = (const float*)d_in[1];   // [2304,768]
  const float* Wp = (const float*)d_in[2];   // [768,768]
  float* out = (float*)d_out;                // [2,2048,768] fp32

  unsigned short* ws = (unsigned short*)d_ws;
  unsigned short* xb  = ws;                  // 4096*768
  unsigned short* Wab = xb  + 3145728;       // 2304*768
  unsigned short* Wpb = Wab + 1769472;       // 768*768
  unsigned short* Qb  = Wpb + 589824;        // 24*2048*64 (pre-scaled)
  unsigned short* Kb  = Qb  + 3145728;
  unsigned short* Vt  = Kb  + 3145728;       // [24][64][2048]
  float*          Oacc = (float*)(Vt + 3145728);  // 24*2048*64 fp32
  float*          Lacc = Oacc + 3145728;          // 24*2048 fp32

  hipMemsetAsync(Oacc, 0, (3145728 + 49152) * sizeof(float), stream);

  cvt_all<<<(XN4 + WAN4 + WPN4) / 256, 256, 0, stream>>>(x, Wa, Wp, xb, Wab, Wpb);

  gemm_qkv<<<dim3(32, 18), 256, 0, stream>>>(xb, Wab, Qb, Kb, Vt);

  attn_part<<<960, 256, 0, stream>>>(Qb, Kb, Vt, Oacc, Lacc);

  gemm_proj<<<dim3(64, 6), 256, 0, stream>>>(Oacc, Lacc, Wpb, out);
}

// Round 7
// 180.783 us; speedup vs baseline: 1.0247x; 1.0247x over previous
//
#include <hip/hip_runtime.h>

typedef __attribute__((ext_vector_type(8))) short bf16x8;
typedef __attribute__((ext_vector_type(4))) float f32x4;

// fp32 -> bf16 (round-to-nearest-even), finite inputs only
__device__ __forceinline__ unsigned short f2b(float f) {
  union { float f; unsigned u; } v; v.f = f;
  return (unsigned short)((v.u + 0x7FFFu + ((v.u >> 16) & 1u)) >> 16);
}
// cheap round-half-up (for P only; half-ULP bias cancels in softmax ratio)
__device__ __forceinline__ unsigned short f2b_fast(float f) {
  union { float f; unsigned u; } v; v.f = f;
  return (unsigned short)((v.u + 0x8000u) >> 16);
}

// Fused fp32->bf16 cast for x, W_attn, W_proj (one launch)
#define XN4   786432   // 4096*768/4
#define WAN4  442368   // 2304*768/4
#define WPN4  147456   // 768*768/4
__global__ void cvt_all(const float* __restrict__ x, const float* __restrict__ Wa,
                        const float* __restrict__ Wp,
                        unsigned short* __restrict__ xb, unsigned short* __restrict__ Wab,
                        unsigned short* __restrict__ Wpb) {
  int i = blockIdx.x * 256 + threadIdx.x;
  const float* src; unsigned short* dst; int off;
  if (i < XN4)            { src = x;  dst = xb;  off = i; }
  else if (i < XN4 + WAN4){ src = Wa; dst = Wab; off = i - XN4; }
  else                    { src = Wp; dst = Wpb; off = i - XN4 - WAN4; }
  float4 f = reinterpret_cast<const float4*>(src)[off];
  ushort4 o;
  o.x = f2b(f.x); o.y = f2b(f.y); o.z = f2b(f.z); o.w = f2b(f.w);
  reinterpret_cast<ushort4*>(dst)[off] = o;
}

// qkv = x @ W_attn^T. 128x128x64 tiles, DOUBLE-BUFFERED global_load_lds:
// barrier drains the DMA issued one tile ago (already complete), next DMA
// issues immediately after, compute proceeds with no wait on it.
// V-blocks (n0>=1536) swap MFMA operands so the Vt [BH][64][T] store is
// contiguous in t.
__global__ __launch_bounds__(256, 2)
void gemm_qkv(const unsigned short* __restrict__ A,
              const unsigned short* __restrict__ Bm,
              unsigned short* __restrict__ qb,
              unsigned short* __restrict__ kb_,
              unsigned short* __restrict__ vt) {
  __shared__ unsigned short As[2][128 * 64];  // 2 x 16 KB
  __shared__ unsigned short Bs[2][128 * 64];  // 2 x 16 KB
  const int K = 768;
  int tid = threadIdx.x;
  int wave = tid >> 6, lane = tid & 63;
  int quad = lane >> 4, l16 = lane & 15;
  int m0 = blockIdx.x * 128, n0 = blockIdx.y * 128;
  int wm = (wave & 1) * 64, wn = (wave >> 1) * 64;
  bool vswap = (n0 >= 1536);

  int srow = lane >> 3;                   // 0..7
  int scol = ((lane & 7) ^ srow) << 3;    // swizzled global chunk * 8 elems

  auto stage = [&](int k0, int buf) {
#pragma unroll
    for (int i = 0; i < 4; ++i) {
      int r = wave * 32 + i * 8;
      __builtin_amdgcn_global_load_lds(
          (const __attribute__((address_space(1))) unsigned int*)(A + (size_t)(m0 + r + srow) * K + k0 + scol),
          (__attribute__((address_space(3))) unsigned int*)(&As[buf][r * 64]), 16, 0, 0);
      __builtin_amdgcn_global_load_lds(
          (const __attribute__((address_space(1))) unsigned int*)(Bm + (size_t)(n0 + r + srow) * K + k0 + scol),
          (__attribute__((address_space(3))) unsigned int*)(&Bs[buf][r * 64]), 16, 0, 0);
    }
  };

  f32x4 acc[4][4] = {};
  stage(0, 0);
  int cur = 0;

  for (int k0 = 0; k0 < K; k0 += 64) {
    __syncthreads();  // drains DMA for buf 'cur' (issued one tile ago)
    if (k0 + 64 < K) stage(k0 + 64, cur ^ 1);
#pragma unroll
    for (int kb = 0; kb < 2; ++kb) {
      int ch = (((kb << 2) | quad) ^ (l16 & 7)) << 3;
      bf16x8 af[4], bf[4];
#pragma unroll
      for (int i = 0; i < 4; ++i)
        af[i] = *reinterpret_cast<const bf16x8*>(&As[cur][(wm + i * 16 + l16) * 64 + ch]);
#pragma unroll
      for (int j = 0; j < 4; ++j)
        bf[j] = *reinterpret_cast<const bf16x8*>(&Bs[cur][(wn + j * 16 + l16) * 64 + ch]);
      if (!vswap) {
#pragma unroll
        for (int i = 0; i < 4; ++i)
#pragma unroll
          for (int j = 0; j < 4; ++j)
            acc[i][j] = __builtin_amdgcn_mfma_f32_16x16x32_bf16(af[i], bf[j], acc[i][j], 0, 0, 0);
      } else {
#pragma unroll
        for (int i = 0; i < 4; ++i)
#pragma unroll
          for (int j = 0; j < 4; ++j)
            acc[i][j] = __builtin_amdgcn_mfma_f32_16x16x32_bf16(bf[j], af[i], acc[i][j], 0, 0, 0);
      }
    }
    cur ^= 1;
  }

  const float scale2 = 0.125f * 1.44269504089f;  // 1/sqrt(64) * log2(e), folded into Q
  if (!vswap) {
#pragma unroll
    for (int i = 0; i < 4; ++i) {
      int mbase = m0 + wm + i * 16 + quad * 4;
#pragma unroll
      for (int j = 0; j < 4; ++j) {
        int f = n0 + wn + j * 16 + l16;
        int which = f / 768;
        int f2 = f - which * 768;
        int h = f2 >> 6, d = f2 & 63;
#pragma unroll
        for (int r = 0; r < 4; ++r) {
          int m = mbase + r;
          int b = m >> 11, t = m & 2047;
          int bh = b * 12 + h;
          if (which == 0) qb[((size_t)(bh * 2048 + t)) * 64 + d] = f2b(acc[i][j][r] * scale2);
          else            kb_[((size_t)(bh * 2048 + t)) * 64 + d] = f2b(acc[i][j][r]);
        }
      }
    }
  } else {
#pragma unroll
    for (int j = 0; j < 4; ++j) {
      int fbase = n0 + wn + j * 16 + quad * 4 - 1536;
#pragma unroll
      for (int i = 0; i < 4; ++i) {
        int t_g = m0 + wm + i * 16 + l16;
        int b = t_g >> 11, t = t_g & 2047;
#pragma unroll
        for (int r = 0; r < 4; ++r) {
          int f2 = fbase + r;
          int h = f2 >> 6, d = f2 & 63;
          int bh = b * 12 + h;
          vt[((size_t)(bh * 64 + d)) * 2048 + t] = f2b(acc[i][j][r]);
        }
      }
    }
  }
}

// ---------------- Split-K flash attention ----------------
// Block = 4 waves on one (bh, 128-row Q-block, 256-key chunk). Double-
// buffered K/V DMA (prefetch one tile ahead; barrier only drains the
// already-complete previous DMA). XCD-aware mapping: blockIdx&7 selects the
// XCD (round-robin heuristic), each XCD owns 3 bh -> K/V/Q working set
// ~2.25 MB fits the 4 MB per-XCD L2. No-max softmax (m=0, Q pre-scaled);
// row-sum via ones-MFMA; partials atomicAdd into fp32 Oacc/Lacc.
#define CK 256

__global__ __launch_bounds__(256, 3)
void attn_part(const unsigned short* __restrict__ Qb,
               const unsigned short* __restrict__ Kb,
               const unsigned short* __restrict__ Vt,
               float* __restrict__ Oacc, float* __restrict__ Lacc) {
  __shared__ unsigned short Ks[2][64 * 64];   // 2 x 8 KB
  __shared__ unsigned short Vs[2][64 * 64];   // 2 x 8 KB
  __shared__ unsigned short P[4 * 32 * 64];   // 16 KB  (total 48 KB)
  const int T = 2048, D = 64;
  int wave = threadIdx.x >> 6, lane = threadIdx.x & 63;
  int quad = lane >> 4, l16 = lane & 15;

  // block -> (xcd, bh, qblock b, chunk c): 1728 = 8 xcd * 3 bh * 72 pairs
  int flat = blockIdx.x;
  int xcd = flat & 7;
  int ix = flat >> 3;              // 0..215
  int bh = xcd * 3 + ix / 72;
  int r = ix % 72;
  int b = 15;
#pragma unroll
  for (int i = 0; i < 16; ++i) {
    int nb = (i >> 1) + 1;
    if (r < nb) { b = i; break; }
    r -= nb;
  }
  int c = r;
  int q0 = b * 128;
  int qrow = q0 + wave * 32;
  int kbeg = c * CK;
  int kend = kbeg + CK; if (kend > q0 + 128) kend = q0 + 128;

  const unsigned short* Qp = Qb + (size_t)bh * T * D;
  const unsigned short* Kp = Kb + (size_t)bh * T * D;
  const unsigned short* Vp = Vt + (size_t)bh * D * T;
  unsigned short* Pw = P + wave * 32 * 64;

  int srow = lane >> 3;
  int scol = ((lane & 7) ^ srow) << 3;

  auto stage = [&](int k0, int buf) {
#pragma unroll
    for (int i = 0; i < 2; ++i) {
      int rr = wave * 16 + i * 8;
      __builtin_amdgcn_global_load_lds(
          (const __attribute__((address_space(1))) unsigned int*)(Kp + (size_t)(k0 + rr + srow) * D + scol),
          (__attribute__((address_space(3))) unsigned int*)(&Ks[buf][rr * 64]), 16, 0, 0);
      __builtin_amdgcn_global_load_lds(
          (const __attribute__((address_space(1))) unsigned int*)(Vp + (size_t)(rr + srow) * T + k0 + scol),
          (__attribute__((address_space(3))) unsigned int*)(&Vs[buf][rr * 64]), 16, 0, 0);
    }
  };

  bf16x8 aq[2][2];
#pragma unroll
  for (int qi = 0; qi < 2; ++qi)
#pragma unroll
    for (int cc = 0; cc < 2; ++cc)
      aq[qi][cc] = *reinterpret_cast<const bf16x8*>(
          Qp + (qrow + qi * 16 + l16) * D + cc * 32 + quad * 8);

  bf16x8 ones;
#pragma unroll
  for (int e = 0; e < 8; ++e) ones[e] = (short)0x3F80;  // bf16 1.0

  f32x4 o[2][4] = {};
  f32x4 lacc[2] = {};
  int pswr = (l16 & 7) ^ (l16 >> 3);  // P-read row swizzle

  stage(kbeg, 0);
  int cur = 0;

  for (int k0 = kbeg; k0 < kend; k0 += 64) {
    __syncthreads();  // drains DMA for buf 'cur' (one tile of latency cover)
    if (k0 + 64 < kend) stage(k0 + 64, cur ^ 1);

    if (k0 <= qrow + 31) {  // not fully masked for this wave
      // ---- S = Q K^T ----
      f32x4 sacc[2][4] = {};
#pragma unroll
      for (int nt = 0; nt < 4; ++nt) {
        bf16x8 bk0 = *reinterpret_cast<const bf16x8*>(&Ks[cur][(nt * 16 + l16) * 64 + ((quad ^ (l16 & 7)) << 3)]);
        bf16x8 bk1 = *reinterpret_cast<const bf16x8*>(&Ks[cur][(nt * 16 + l16) * 64 + (((4 | quad) ^ (l16 & 7)) << 3)]);
#pragma unroll
        for (int qi = 0; qi < 2; ++qi) {
          sacc[qi][nt] = __builtin_amdgcn_mfma_f32_16x16x32_bf16(aq[qi][0], bk0, sacc[qi][nt], 0, 0, 0);
          sacc[qi][nt] = __builtin_amdgcn_mfma_f32_16x16x32_bf16(aq[qi][1], bk1, sacc[qi][nt], 0, 0, 0);
        }
      }

      // ---- p = 2^s ; mask only diagonal-straddling tiles ----
      if (k0 + 63 > qrow) {
#pragma unroll
        for (int qi = 0; qi < 2; ++qi)
#pragma unroll
          for (int nt = 0; nt < 4; ++nt) {
            int col = k0 + nt * 16 + l16;
#pragma unroll
            for (int rr = 0; rr < 4; ++rr) {
              int row = qrow + qi * 16 + quad * 4 + rr;
              sacc[qi][nt][rr] = (col <= row) ? sacc[qi][nt][rr] : -1e30f;
            }
          }
      }
#pragma unroll
      for (int qi = 0; qi < 2; ++qi)
#pragma unroll
        for (int nt = 0; nt < 4; ++nt)
#pragma unroll
          for (int rr = 0; rr < 4; ++rr)
            sacc[qi][nt][rr] = exp2f(sacc[qi][nt][rr]);

      // ---- P: C-layout -> wave-private LDS (swizzled) -> A-layout ----
#pragma unroll
      for (int qi = 0; qi < 2; ++qi)
#pragma unroll
        for (int rr = 0; rr < 4; ++rr) {
          int prow = qi * 16 + quad * 4 + rr;
          int psw = (prow & 7) ^ ((prow >> 3) & 1);
#pragma unroll
          for (int nt = 0; nt < 4; ++nt)
            Pw[prow * 64 + (((nt * 2 + (l16 >> 3)) ^ psw) << 3) + (l16 & 7)] = f2b_fast(sacc[qi][nt][rr]);
        }
      __asm__ volatile("s_waitcnt lgkmcnt(0)" ::: "memory");

      // ---- O += P V ; l += P * ones ----
      bf16x8 vf[4][2];
#pragma unroll
      for (int dt = 0; dt < 4; ++dt) {
        vf[dt][0] = *reinterpret_cast<const bf16x8*>(&Vs[cur][(dt * 16 + l16) * 64 + ((quad ^ (l16 & 7)) << 3)]);
        vf[dt][1] = *reinterpret_cast<const bf16x8*>(&Vs[cur][(dt * 16 + l16) * 64 + (((4 | quad) ^ (l16 & 7)) << 3)]);
      }
#pragma unroll
      for (int qi = 0; qi < 2; ++qi) {
        bf16x8 ap0 = *reinterpret_cast<const bf16x8*>(Pw + (qi * 16 + l16) * 64 + ((quad ^ pswr) << 3));
        bf16x8 ap1 = *reinterpret_cast<const bf16x8*>(Pw + (qi * 16 + l16) * 64 + (((4 | quad) ^ pswr) << 3));
#pragma unroll
        for (int dt = 0; dt < 4; ++dt) {
          o[qi][dt] = __builtin_amdgcn_mfma_f32_16x16x32_bf16(ap0, vf[dt][0], o[qi][dt], 0, 0, 0);
          o[qi][dt] = __builtin_amdgcn_mfma_f32_16x16x32_bf16(ap1, vf[dt][1], o[qi][dt], 0, 0, 0);
        }
        lacc[qi] = __builtin_amdgcn_mfma_f32_16x16x32_bf16(ap0, ones, lacc[qi], 0, 0, 0);
        lacc[qi] = __builtin_amdgcn_mfma_f32_16x16x32_bf16(ap1, ones, lacc[qi], 0, 0, 0);
      }
      __asm__ volatile("" ::: "memory");
    }
    cur ^= 1;
  }

  // accumulate partials: fp32 atomics (plain sums combine exactly, m fixed)
#pragma unroll
  for (int qi = 0; qi < 2; ++qi)
#pragma unroll
    for (int dt = 0; dt < 4; ++dt)
#pragma unroll
      for (int rr = 0; rr < 4; ++rr) {
        int row = qrow + qi * 16 + quad * 4 + rr;
        atomicAdd(&Oacc[((size_t)(bh * T + row)) * 64 + dt * 16 + l16], o[qi][dt][rr]);
      }
  if (l16 == 0) {
#pragma unroll
    for (int qi = 0; qi < 2; ++qi)
#pragma unroll
      for (int rr = 0; rr < 4; ++rr)
        atomicAdd(&Lacc[bh * T + qrow + qi * 16 + quad * 4 + rr], lacc[qi][rr]);
  }
}

// out = normalize(Oacc/Lacc) @ W_proj^T, fp32 out. 64x128x64 tiles.
// Fully pipelined: B via double-buffered DMA; A (Oacc) global loads issued
// one tile ahead into regs, cvt+ds_write into the next As buffer while
// computing the current one.
__global__ __launch_bounds__(256, 2)
void gemm_proj(const float* __restrict__ Oacc, const float* __restrict__ Lacc,
               const unsigned short* __restrict__ Wpb, float* __restrict__ out) {
  __shared__ unsigned short As[2][64 * 64];   // 2 x 8 KB
  __shared__ unsigned short Bs[2][128 * 64];  // 2 x 16 KB  (total 48 KB)
  int tid = threadIdx.x;
  int wave = tid >> 6, lane = tid & 63;
  int quad = lane >> 4, l16 = lane & 15;
  int m0 = blockIdx.x * 64, n0 = blockIdx.y * 128;
  int wm = (wave & 1) * 32, wn = (wave >> 1) * 64;

  int srow = lane >> 3;
  int scol = ((lane & 7) ^ srow) << 3;

  int arow = tid >> 2;           // 0..63
  int acg = (tid & 3) * 2;       // 16-col group: cols acg*8 .. acg*8+15
  int t_g = m0 + arow;
  int bb = t_g >> 11, tt = t_g & 2047;
  int asw = arow & 7;

  auto stageB = [&](int k0, int buf) {
#pragma unroll
    for (int i = 0; i < 4; ++i) {
      int r = wave * 32 + i * 8;
      __builtin_amdgcn_global_load_lds(
          (const __attribute__((address_space(1))) unsigned int*)(Wpb + (size_t)(n0 + r + srow) * 768 + k0 + scol),
          (__attribute__((address_space(3))) unsigned int*)(&Bs[buf][r * 64]), 16, 0, 0);
    }
  };
  auto loadA = [&](int k0, float4* a, float& rl) {
    int h = k0 >> 6;
    const float* arp = Oacc + ((size_t)((bb * 12 + h) * 2048 + tt)) * 64 + acg * 8;
    rl = 1.0f / Lacc[(bb * 12 + h) * 2048 + tt];
    a[0] = reinterpret_cast<const float4*>(arp)[0];
    a[1] = reinterpret_cast<const float4*>(arp)[1];
    a[2] = reinterpret_cast<const float4*>(arp)[2];
    a[3] = reinterpret_cast<const float4*>(arp)[3];
  };
  auto writeA = [&](const float4* a, float rl, int buf) {
    bf16x8 p0, p1;
    p0[0] = (short)f2b(a[0].x * rl); p0[1] = (short)f2b(a[0].y * rl);
    p0[2] = (short)f2b(a[0].z * rl); p0[3] = (short)f2b(a[0].w * rl);
    p0[4] = (short)f2b(a[1].x * rl); p0[5] = (short)f2b(a[1].y * rl);
    p0[6] = (short)f2b(a[1].z * rl); p0[7] = (short)f2b(a[1].w * rl);
    p1[0] = (short)f2b(a[2].x * rl); p1[1] = (short)f2b(a[2].y * rl);
    p1[2] = (short)f2b(a[2].z * rl); p1[3] = (short)f2b(a[2].w * rl);
    p1[4] = (short)f2b(a[3].x * rl); p1[5] = (short)f2b(a[3].y * rl);
    p1[6] = (short)f2b(a[3].z * rl); p1[7] = (short)f2b(a[3].w * rl);
    *reinterpret_cast<bf16x8*>(&As[buf][arow * 64 + ((acg ^ asw) << 3)]) = p0;
    *reinterpret_cast<bf16x8*>(&As[buf][arow * 64 + (((acg + 1) ^ asw) << 3)]) = p1;
  };

  f32x4 acc[2][4] = {};

  float4 aP[4], aN[4];
  float rlP, rlN;
  stageB(0, 0);
  loadA(0, aP, rlP);
  loadA(64, aN, rlN);
  writeA(aP, rlP, 0);
  int cur = 0;

  for (int k0 = 0; k0 < 768; k0 += 64) {
    __syncthreads();  // drains Bs[cur] DMA + As[cur] ds_writes + aN loads
    if (k0 + 64 < 768) {
      stageB(k0 + 64, cur ^ 1);
      writeA(aN, rlN, cur ^ 1);
      if (k0 + 128 < 768) loadA(k0 + 128, aN, rlN);
    }
#pragma unroll
    for (int kb = 0; kb < 2; ++kb) {
      int ch = (((kb << 2) | quad) ^ (l16 & 7)) << 3;
      bf16x8 af[2], bf[4];
#pragma unroll
      for (int i = 0; i < 2; ++i)
        af[i] = *reinterpret_cast<const bf16x8*>(&As[cur][(wm + i * 16 + l16) * 64 + ch]);
#pragma unroll
      for (int j = 0; j < 4; ++j)
        bf[j] = *reinterpret_cast<const bf16x8*>(&Bs[cur][(wn + j * 16 + l16) * 64 + ch]);
#pragma unroll
      for (int i = 0; i < 2; ++i)
#pragma unroll
        for (int j = 0; j < 4; ++j)
          acc[i][j] = __builtin_amdgcn_mfma_f32_16x16x32_bf16(af[i], bf[j], acc[i][j], 0, 0, 0);
    }
    cur ^= 1;
  }

#pragma unroll
  for (int i = 0; i < 2; ++i) {
    int mbase = m0 + wm + i * 16 + quad * 4;
#pragma unroll
    for (int j = 0; j < 4; ++j) {
      int col = n0 + wn + j * 16 + l16;
#pragma unroll
      for (int r = 0; r < 4; ++r)
        out[(size_t)(mbase + r) * 768 + col] = acc[i][j][r];
    }
  }
}

extern "C" void kernel_launch(void* const* d_in, const int* in_sizes, int n_in,
                              void* d_out, int out_size, void* d_ws, size_t ws_size,
                              hipStream_t stream) {
  const float* x  = (const float*)d_in[0];   // [2,2048,768]
  const float* Wa = (const float*)d_in[1];   // [2304,768]
  const float* Wp = (const float*)d_in[2];   // [768,768]
  float* out = (float*)d_out;                // [2,2048,768] fp32

  unsigned short* ws = (unsigned short*)d_ws;
  unsigned short* xb  = ws;                  // 4096*768
  unsigned short* Wab = xb  + 3145728;       // 2304*768
  unsigned short* Wpb = Wab + 1769472;       // 768*768
  unsigned short* Qb  = Wpb + 589824;        // 24*2048*64 (pre-scaled)
  unsigned short* Kb  = Qb  + 3145728;
  unsigned short* Vt  = Kb  + 3145728;       // [24][64][2048]
  float*          Oacc = (float*)(Vt + 3145728);  // 24*2048*64 fp32
  float*          Lacc = Oacc + 3145728;          // 24*2048 fp32

  hipMemsetAsync(Oacc, 0, (3145728 + 49152) * sizeof(float), stream);

  cvt_all<<<(XN4 + WAN4 + WPN4) / 256, 256, 0, stream>>>(x, Wa, Wp, xb, Wab, Wpb);

  gemm_qkv<<<dim3(32, 18), 256, 0, stream>>>(xb, Wab, Qb, Kb, Vt);

  attn_part<<<1728, 256, 0, stream>>>(Qb, Kb, Vt, Oacc, Lacc);

  gemm_proj<<<dim3(64, 6), 256, 0, stream>>>(Oacc, Lacc, Wpb, out);
}